// Round 1
// baseline (262.313 us; speedup 1.0000x reference)
//
#include <hip/hip_runtime.h>
#include <math.h>

// ---------------------------------------------------------------------------
// f32 conv1x1 GEMM: Y[p][o] (pixel-major) or Y[b][o][hw] (channel-major)
//   = bias[o] + sum_c W[o][c] * X(...)
// X layout: channel-major [b][Cin][HW] (PIX_IN=false) or pixel-major [p][Cin]
// Two weight/output sets (a,b) selected by blockIdx.y < n_ot_a  (fused k+v).
// Tiling: PX pixels x OT outs per block, KC=64 K-chunk, 256 threads,
// thread computes OPT x PPT accumulators. PPT must be 4 here.
// ---------------------------------------------------------------------------
template<int PX, int OT, int OPT, int PPT, bool PIX_IN, bool PIX_OUT>
__global__ __launch_bounds__(256) void conv1x1_k(
    const float* __restrict__ X,
    const float* __restrict__ Wa, const float* __restrict__ ba, float* __restrict__ Ya,
    const float* __restrict__ Wb, const float* __restrict__ bb, float* __restrict__ Yb,
    int Cin, int HW, int n_ot_a)
{
    constexpr int KC  = 64;
    constexpr int OGN = OT / OPT;          // # out-groups (=16 for both configs)
    static_assert(PPT == 4, "PPT must be 4");
    static_assert((PX / PPT) * (OT / OPT) == 256, "bad tile config");

    __shared__ float Xs[KC][PX + 4];
    __shared__ float Ws[KC][OT + 4];

    const int t  = threadIdx.x;
    const int p0 = blockIdx.x * PX;
    int oy = blockIdx.y;
    const float* W; const float* bias; float* Y;
    if (oy < n_ot_a) { W = Wa; bias = ba; Y = Ya; }
    else             { W = Wb; bias = bb; Y = Yb; oy -= n_ot_a; }
    const int o0  = oy * OT;
    const int b   = p0 / HW;
    const int hw0 = p0 % HW;

    const int og = t % OGN;
    const int pg = t / OGN;

    float acc[OPT][PPT];
    #pragma unroll
    for (int i = 0; i < OPT; i++)
        #pragma unroll
        for (int j = 0; j < PPT; j++) acc[i][j] = 0.f;

    for (int c0 = 0; c0 < Cin; c0 += KC) {
        __syncthreads();
        // ---- stage X tile ----
        #pragma unroll
        for (int i = 0; i < KC * PX / 256; i++) {
            const int f = t + i * 256;
            int ci, px;
            if (PIX_IN) { ci = f % KC; px = f / KC; }   // lanes: consecutive c (coalesced)
            else        { ci = f / PX; px = f % PX; }   // lanes: consecutive px (coalesced)
            float v;
            if (PIX_IN) v = X[(p0 + px) * Cin + (c0 + ci)];
            else        v = X[(b * Cin + c0 + ci) * HW + hw0 + px];
            Xs[ci][px] = v;
        }
        // ---- stage W tile (transposed: Ws[ci][o]) ----
        #pragma unroll
        for (int i = 0; i < KC * OT / 256; i++) {
            const int f  = t + i * 256;
            const int o  = f / KC;
            const int ci = f % KC;
            Ws[ci][o] = W[(o0 + o) * Cin + (c0 + ci)];
        }
        __syncthreads();
        // ---- compute ----
        #pragma unroll 8
        for (int ci = 0; ci < KC; ci++) {
            float w[OPT], x[PPT];
            if constexpr (OPT == 4) {
                float4 wv = *(const float4*)&Ws[ci][og * OPT];
                w[0] = wv.x; w[1] = wv.y; w[2] = wv.z; w[3] = wv.w;
            } else {
                float2 wv = *(const float2*)&Ws[ci][og * OPT];
                w[0] = wv.x; w[1] = wv.y;
            }
            {
                float4 xv = *(const float4*)&Xs[ci][pg * PPT];
                x[0] = xv.x; x[1] = xv.y; x[2] = xv.z; x[3] = xv.w;
            }
            #pragma unroll
            for (int i = 0; i < OPT; i++)
                #pragma unroll
                for (int j = 0; j < PPT; j++)
                    acc[i][j] += w[i] * x[j];
        }
    }

    // ---- epilogue ----
    float bi[OPT];
    #pragma unroll
    for (int i = 0; i < OPT; i++) bi[i] = bias[o0 + og * OPT + i];

    if (PIX_OUT) {
        #pragma unroll
        for (int j = 0; j < PPT; j++) {
            float* yp = Y + (size_t)(p0 + pg * PPT + j) * 256 + o0 + og * OPT;
            if constexpr (OPT == 4) {
                float4 ov;
                ov.x = acc[0][j] + bi[0]; ov.y = acc[1][j] + bi[1];
                ov.z = acc[2][j] + bi[2]; ov.w = acc[3][j] + bi[3];
                *(float4*)yp = ov;
            } else {
                float2 ov;
                ov.x = acc[0][j] + bi[0]; ov.y = acc[1][j] + bi[1];
                *(float2*)yp = ov;
            }
        }
    } else {
        #pragma unroll
        for (int i = 0; i < OPT; i++) {
            float* yp = Y + (size_t)(b * 256 + o0 + og * OPT + i) * HW + hw0 + pg * PPT;
            float4 ov;
            ov.x = acc[i][0] + bi[i]; ov.y = acc[i][1] + bi[i];
            ov.z = acc[i][2] + bi[i]; ov.w = acc[i][3] + bi[i];
            *(float4*)yp = ov;
        }
    }
}

// ---------------------------------------------------------------------------
// Attention: one thread per (b, head, query-pixel). Online softmax over the
// K=WS*WS dilated neighbors at the coarse anchor (qy/SF, qx/SF).
// k/v are pixel-major [b][hm][wm][256] so each thread streams contiguous rows.
// Output goes to fusedT[p][512] at channel offset s_off + n*32.
// ---------------------------------------------------------------------------
template<int WS, int DIL, int SF, int HM, int WM>
__device__ __forceinline__ void attn_one(
    const float* __restrict__ qT, const float* __restrict__ kT,
    const float* __restrict__ vT, float* __restrict__ fusedT,
    int b, int n, int tile, int t, int s_off)
{
    const int qy = (tile >> 2) * 16 + (t >> 4);
    const int qx = (tile & 3) * 16 + (t & 15);
    const int p  = (b * 64 + qy) * 64 + qx;

    float q[32], o[32];
    const float* qp = qT + (size_t)p * 256 + n * 32;
    #pragma unroll
    for (int i = 0; i < 8; i++) {
        float4 v = *(const float4*)(qp + i * 4);
        q[i*4] = v.x; q[i*4+1] = v.y; q[i*4+2] = v.z; q[i*4+3] = v.w;
    }
    #pragma unroll
    for (int d = 0; d < 32; d++) o[d] = 0.f;

    float m = -INFINITY, l = 0.f;
    const int ay = qy / SF, ax = qx / SF;
    const float scale = 0.17677669529663687f;   // 32^-0.5

    for (int jy = 0; jy < WS; jy++) {
        const int ym = ay + (jy - WS / 2) * DIL;
        if (ym < 0 || ym >= HM) continue;
        for (int jx = 0; jx < WS; jx++) {
            const int xm = ax + (jx - WS / 2) * DIL;
            if (xm < 0 || xm >= WM) continue;
            const int base = (((b * HM) + ym) * WM + xm) * 256 + n * 32;
            const float* kp = kT + base;
            float dot = 0.f;
            #pragma unroll
            for (int i = 0; i < 8; i++) {
                float4 kv = *(const float4*)(kp + i * 4);
                dot += q[i*4] * kv.x + q[i*4+1] * kv.y + q[i*4+2] * kv.z + q[i*4+3] * kv.w;
            }
            const float sc = dot * scale;
            if (sc > m) {                     // rescale only on new max
                const float corr = __expf(m - sc);
                l *= corr;
                #pragma unroll
                for (int d = 0; d < 32; d++) o[d] *= corr;
                m = sc;
            }
            const float w = __expf(sc - m);
            l += w;
            const float* vp = vT + base;
            #pragma unroll
            for (int i = 0; i < 8; i++) {
                float4 vv = *(const float4*)(vp + i * 4);
                o[i*4]   += w * vv.x; o[i*4+1] += w * vv.y;
                o[i*4+2] += w * vv.z; o[i*4+3] += w * vv.w;
            }
        }
    }

    const float inv = 1.f / l;
    float* yp = fusedT + (size_t)p * 512 + s_off + n * 32;
    #pragma unroll
    for (int i = 0; i < 8; i++) {
        float4 ov;
        ov.x = o[i*4] * inv;   ov.y = o[i*4+1] * inv;
        ov.z = o[i*4+2] * inv; ov.w = o[i*4+3] * inv;
        *(float4*)(yp + i * 4) = ov;
    }
}

__global__ __launch_bounds__(256) void attn_k(
    const float* __restrict__ qT,
    const float* __restrict__ k0T, const float* __restrict__ v0T,
    const float* __restrict__ k1T, const float* __restrict__ v1T,
    float* __restrict__ fusedT)
{
    const int x = blockIdx.x;
    const int t = threadIdx.x;
    const int s = x >> 8;          // 0: scale0 (win7,dil1,sf2), 1: scale1 (win5,dil2,sf4)
    const int r = x & 255;
    const int tile = r & 15;
    const int n = (r >> 4) & 7;
    const int b = r >> 7;
    if (s == 0) attn_one<7, 1, 2, 32, 32>(qT, k0T, v0T, fusedT, b, n, tile, t, 0);
    else        attn_one<5, 2, 4, 16, 16>(qT, k1T, v1T, fusedT, b, n, tile, t, 256);
}

// ---------------------------------------------------------------------------
extern "C" void kernel_launch(void* const* d_in, const int* in_sizes, int n_in,
                              void* d_out, int out_size, void* d_ws, size_t ws_size,
                              hipStream_t stream)
{
    const float* query = (const float*)d_in[0];
    const float* mem0  = (const float*)d_in[1];
    const float* mem1  = (const float*)d_in[2];
    const float* Wq    = (const float*)d_in[3];  const float* bq    = (const float*)d_in[4];
    const float* Wk0   = (const float*)d_in[5];  const float* bk0   = (const float*)d_in[6];
    const float* Wv0   = (const float*)d_in[7];  const float* bv0   = (const float*)d_in[8];
    const float* Wk1   = (const float*)d_in[9];  const float* bk1   = (const float*)d_in[10];
    const float* Wv1   = (const float*)d_in[11]; const float* bv1   = (const float*)d_in[12];
    const float* Wfuse = (const float*)d_in[13]; const float* bfuse = (const float*)d_in[14];
    float* out = (float*)d_out;

    // workspace layout (floats): qT | k0T | v0T | k1T | v1T | fusedT  (~30.4 MB)
    float* qT     = (float*)d_ws;
    float* k0T    = qT  + (size_t)8192 * 256;
    float* v0T    = k0T + (size_t)2048 * 256;
    float* k1T    = v0T + (size_t)2048 * 256;
    float* v1T    = k1T + (size_t)512 * 256;
    float* fusedT = v1T + (size_t)512 * 256;

    // 1) q = Wq * query + bq          -> qT [8192][256]
    conv1x1_k<64, 64, 4, 4, false, true><<<dim3(128, 4), 256, 0, stream>>>(
        query, Wq, bq, qT, Wq, bq, qT, 256, 4096, 4);
    // 2) k0,v0 = Wk0/Wv0 * mem0       -> k0T/v0T [2048][256]
    conv1x1_k<64, 64, 4, 4, false, true><<<dim3(32, 8), 256, 0, stream>>>(
        mem0, Wk0, bk0, k0T, Wv0, bv0, v0T, 384, 1024, 4);
    // 3) k1,v1 = Wk1/Wv1 * mem1       -> k1T/v1T [512][256]
    conv1x1_k<64, 32, 2, 4, false, true><<<dim3(8, 16), 256, 0, stream>>>(
        mem1, Wk1, bk1, k1T, Wv1, bv1, v1T, 768, 256, 8);
    // 4) both attention scales        -> fusedT [8192][512]
    attn_k<<<dim3(512), 256, 0, stream>>>(qT, k0T, v0T, k1T, v1T, fusedT);
    // 5) out = Wfuse * fused + bfuse  -> d_out [2][256][64][64]
    conv1x1_k<64, 64, 4, 4, true, false><<<dim3(128, 4), 256, 0, stream>>>(
        fusedT, Wfuse, bfuse, out, Wfuse, bfuse, out, 512, 4096, 4);
}

// Round 2
// 212.194 us; speedup vs baseline: 1.2362x; 1.2362x over previous
//
#include <hip/hip_runtime.h>
#include <math.h>

// ---------------------------------------------------------------------------
// f32 conv1x1 GEMM device body: Y[p][o] (pixel-major) or Y[b][o][hw]
//   = bias[o] + sum_c W[o][c] * X(...)
// X layout: channel-major [b][Cin][HW] (PIX_IN=false) or pixel-major [p][Cin]
// Tiling: PX pixels x OT outs per block, KC=64 K-chunk, 256 threads,
// thread computes OPT x PPT accumulators. PPT must be 4.
// ---------------------------------------------------------------------------
template<int PX, int OT, int OPT, int PPT, bool PIX_IN, bool PIX_OUT>
__device__ __forceinline__ void conv_dev(
    const float* __restrict__ X, const float* __restrict__ W,
    const float* __restrict__ bias, float* __restrict__ Y,
    int Cin, int HW, int bx, int by, float* smem)
{
    constexpr int KC  = 64;
    constexpr int OGN = OT / OPT;
    static_assert(PPT == 4, "PPT must be 4");
    static_assert((PX / PPT) * (OT / OPT) == 256, "bad tile config");

    float (*Xs)[PX + 4] = (float (*)[PX + 4])smem;
    float (*Ws)[OT + 4] = (float (*)[OT + 4])(smem + KC * (PX + 4));

    const int t   = threadIdx.x;
    const int p0  = bx * PX;
    const int o0  = by * OT;
    const int b   = p0 / HW;
    const int hw0 = p0 % HW;

    const int og = t % OGN;
    const int pg = t / OGN;

    float acc[OPT][PPT];
    #pragma unroll
    for (int i = 0; i < OPT; i++)
        #pragma unroll
        for (int j = 0; j < PPT; j++) acc[i][j] = 0.f;

    for (int c0 = 0; c0 < Cin; c0 += KC) {
        __syncthreads();
        // ---- stage X tile ----
        #pragma unroll
        for (int i = 0; i < KC * PX / 256; i++) {
            const int f = t + i * 256;
            int ci, px;
            if (PIX_IN) { ci = f % KC; px = f / KC; }   // lanes: consecutive c (coalesced)
            else        { ci = f / PX; px = f % PX; }   // lanes: consecutive px (coalesced)
            float v;
            if (PIX_IN) v = X[(size_t)(p0 + px) * Cin + (c0 + ci)];
            else        v = X[(size_t)(b * Cin + c0 + ci) * HW + hw0 + px];
            Xs[ci][px] = v;
        }
        // ---- stage W tile (transposed: Ws[ci][o]) ----
        #pragma unroll
        for (int i = 0; i < KC * OT / 256; i++) {
            const int f  = t + i * 256;
            const int o  = f / KC;
            const int ci = f % KC;
            Ws[ci][o] = W[(size_t)(o0 + o) * Cin + (c0 + ci)];
        }
        __syncthreads();
        // ---- compute ----
        #pragma unroll 8
        for (int ci = 0; ci < KC; ci++) {
            float w[OPT], x[PPT];
            if constexpr (OPT == 4) {
                float4 wv = *(const float4*)&Ws[ci][og * OPT];
                w[0] = wv.x; w[1] = wv.y; w[2] = wv.z; w[3] = wv.w;
            } else {
                float2 wv = *(const float2*)&Ws[ci][og * OPT];
                w[0] = wv.x; w[1] = wv.y;
            }
            {
                float4 xv = *(const float4*)&Xs[ci][pg * PPT];
                x[0] = xv.x; x[1] = xv.y; x[2] = xv.z; x[3] = xv.w;
            }
            #pragma unroll
            for (int i = 0; i < OPT; i++)
                #pragma unroll
                for (int j = 0; j < PPT; j++)
                    acc[i][j] += w[i] * x[j];
        }
    }

    // ---- epilogue ----
    float bi[OPT];
    #pragma unroll
    for (int i = 0; i < OPT; i++) bi[i] = bias[o0 + og * OPT + i];

    if (PIX_OUT) {
        #pragma unroll
        for (int j = 0; j < PPT; j++) {
            float* yp = Y + (size_t)(p0 + pg * PPT + j) * 256 + o0 + og * OPT;
            if constexpr (OPT == 4) {
                float4 ov;
                ov.x = acc[0][j] + bi[0]; ov.y = acc[1][j] + bi[1];
                ov.z = acc[2][j] + bi[2]; ov.w = acc[3][j] + bi[3];
                *(float4*)yp = ov;
            } else {
                float2 ov;
                ov.x = acc[0][j] + bi[0]; ov.y = acc[1][j] + bi[1];
                *(float2*)yp = ov;
            }
        }
    } else {
        #pragma unroll
        for (int i = 0; i < OPT; i++) {
            float* yp = Y + (size_t)(b * 256 + o0 + og * OPT + i) * HW + hw0 + pg * PPT;
            float4 ov;
            ov.x = acc[i][0] + bi[i]; ov.y = acc[i][1] + bi[i];
            ov.z = acc[i][2] + bi[i]; ov.w = acc[i][3] + bi[i];
            *(float4*)yp = ov;
        }
    }
}

// ---------------------------------------------------------------------------
// Fused projection kernel: all three independent input GEMMs in one grid so
// they overlap (one dispatch = full machine instead of 3 serial starved ones).
//   blocks [0,128):   k1/v1 = Wk1/Wv1 * mem1   (Cin=768, HW=256,  OT=32)
//   blocks [128,384): k0/v0 = Wk0/Wv0 * mem0   (Cin=384, HW=1024, OT=64)
//   blocks [384,896): q     = Wq * query       (Cin=256, HW=4096, OT=64)
// ---------------------------------------------------------------------------
__global__ __launch_bounds__(256) void proj_k(
    const float* __restrict__ query, const float* __restrict__ mem0, const float* __restrict__ mem1,
    const float* __restrict__ Wq,  const float* __restrict__ bq,  float* __restrict__ qT,
    const float* __restrict__ Wk0, const float* __restrict__ bk0, float* __restrict__ k0T,
    const float* __restrict__ Wv0, const float* __restrict__ bv0, float* __restrict__ v0T,
    const float* __restrict__ Wk1, const float* __restrict__ bk1, float* __restrict__ k1T,
    const float* __restrict__ Wv1, const float* __restrict__ bv1, float* __restrict__ v1T)
{
    __shared__ float smem[8704];   // max of the three configs (34816 B)
    const int bx = blockIdx.x;
    if (bx < 128) {
        // conv3: grid (8,16)
        int x = bx & 7, y = bx >> 3;
        const float* W; const float* b; float* Y;
        if (y < 8) { W = Wk1; b = bk1; Y = k1T; } else { W = Wv1; b = bv1; Y = v1T; y -= 8; }
        conv_dev<64, 32, 2, 4, false, true>(mem1, W, b, Y, 768, 256, x, y, smem);
    } else if (bx < 384) {
        // conv2: grid (32,8)
        int r = bx - 128;
        int x = r & 31, y = r >> 5;
        const float* W; const float* b; float* Y;
        if (y < 4) { W = Wk0; b = bk0; Y = k0T; } else { W = Wv0; b = bv0; Y = v0T; y -= 4; }
        conv_dev<64, 64, 4, 4, false, true>(mem0, W, b, Y, 384, 1024, x, y, smem);
    } else {
        // conv1: grid (128,4)
        int r = bx - 384;
        int x = r & 127, y = r >> 7;
        conv_dev<64, 64, 4, 4, false, true>(query, Wq, bq, qT, 256, 4096, x, y, smem);
    }
}

// Fuse GEMM (depends on attn): PX=32 -> 1024 blocks for latency hiding.
__global__ __launch_bounds__(256) void fuse_k(
    const float* __restrict__ X, const float* __restrict__ W,
    const float* __restrict__ bias, float* __restrict__ Y)
{
    __shared__ float smem[6656];   // Xs[64][36] + Ws[64][68]
    conv_dev<32, 64, 2, 4, true, false>(X, W, bias, Y, 512, 4096, blockIdx.x, blockIdx.y, smem);
}

// ---------------------------------------------------------------------------
// Attention: one thread per (b, head, query-pixel). Online softmax over the
// K=WS*WS dilated neighbors at the coarse anchor (qy/SF, qx/SF).
// k/v are pixel-major [b][hm][wm][256] so each thread streams contiguous rows.
// Output goes to fusedT[p][512] at channel offset s_off + n*32.
// ---------------------------------------------------------------------------
template<int WS, int DIL, int SF, int HM, int WM>
__device__ __forceinline__ void attn_one(
    const float* __restrict__ qT, const float* __restrict__ kT,
    const float* __restrict__ vT, float* __restrict__ fusedT,
    int b, int n, int tile, int t, int s_off)
{
    const int qy = (tile >> 2) * 16 + (t >> 4);
    const int qx = (tile & 3) * 16 + (t & 15);
    const int p  = (b * 64 + qy) * 64 + qx;

    float q[32], o[32];
    const float* qp = qT + (size_t)p * 256 + n * 32;
    #pragma unroll
    for (int i = 0; i < 8; i++) {
        float4 v = *(const float4*)(qp + i * 4);
        q[i*4] = v.x; q[i*4+1] = v.y; q[i*4+2] = v.z; q[i*4+3] = v.w;
    }
    #pragma unroll
    for (int d = 0; d < 32; d++) o[d] = 0.f;

    float m = -INFINITY, l = 0.f;
    const int ay = qy / SF, ax = qx / SF;
    const float scale = 0.17677669529663687f;   // 32^-0.5

    for (int jy = 0; jy < WS; jy++) {
        const int ym = ay + (jy - WS / 2) * DIL;
        if (ym < 0 || ym >= HM) continue;
        for (int jx = 0; jx < WS; jx++) {
            const int xm = ax + (jx - WS / 2) * DIL;
            if (xm < 0 || xm >= WM) continue;
            const int base = (((b * HM) + ym) * WM + xm) * 256 + n * 32;
            const float* kp = kT + base;
            float dot = 0.f;
            #pragma unroll
            for (int i = 0; i < 8; i++) {
                float4 kv = *(const float4*)(kp + i * 4);
                dot += q[i*4] * kv.x + q[i*4+1] * kv.y + q[i*4+2] * kv.z + q[i*4+3] * kv.w;
            }
            const float sc = dot * scale;
            if (sc > m) {                     // rescale only on new max
                const float corr = __expf(m - sc);
                l *= corr;
                #pragma unroll
                for (int d = 0; d < 32; d++) o[d] *= corr;
                m = sc;
            }
            const float w = __expf(sc - m);
            l += w;
            const float* vp = vT + base;
            #pragma unroll
            for (int i = 0; i < 8; i++) {
                float4 vv = *(const float4*)(vp + i * 4);
                o[i*4]   += w * vv.x; o[i*4+1] += w * vv.y;
                o[i*4+2] += w * vv.z; o[i*4+3] += w * vv.w;
            }
        }
    }

    const float inv = 1.f / l;
    float* yp = fusedT + (size_t)p * 512 + s_off + n * 32;
    #pragma unroll
    for (int i = 0; i < 8; i++) {
        float4 ov;
        ov.x = o[i*4] * inv;   ov.y = o[i*4+1] * inv;
        ov.z = o[i*4+2] * inv; ov.w = o[i*4+3] * inv;
        *(float4*)(yp + i * 4) = ov;
    }
}

__global__ __launch_bounds__(256) void attn_k(
    const float* __restrict__ qT,
    const float* __restrict__ k0T, const float* __restrict__ v0T,
    const float* __restrict__ k1T, const float* __restrict__ v1T,
    float* __restrict__ fusedT)
{
    const int x = blockIdx.x;
    const int t = threadIdx.x;
    const int s = x >> 8;          // 0: scale0 (win7,dil1,sf2), 1: scale1 (win5,dil2,sf4)
    const int r = x & 255;
    const int tile = r & 15;
    const int n = (r >> 4) & 7;
    const int b = r >> 7;
    if (s == 0) attn_one<7, 1, 2, 32, 32>(qT, k0T, v0T, fusedT, b, n, tile, t, 0);
    else        attn_one<5, 2, 4, 16, 16>(qT, k1T, v1T, fusedT, b, n, tile, t, 256);
}

// ---------------------------------------------------------------------------
extern "C" void kernel_launch(void* const* d_in, const int* in_sizes, int n_in,
                              void* d_out, int out_size, void* d_ws, size_t ws_size,
                              hipStream_t stream)
{
    const float* query = (const float*)d_in[0];
    const float* mem0  = (const float*)d_in[1];
    const float* mem1  = (const float*)d_in[2];
    const float* Wq    = (const float*)d_in[3];  const float* bq    = (const float*)d_in[4];
    const float* Wk0   = (const float*)d_in[5];  const float* bk0   = (const float*)d_in[6];
    const float* Wv0   = (const float*)d_in[7];  const float* bv0   = (const float*)d_in[8];
    const float* Wk1   = (const float*)d_in[9];  const float* bk1   = (const float*)d_in[10];
    const float* Wv1   = (const float*)d_in[11]; const float* bv1   = (const float*)d_in[12];
    const float* Wfuse = (const float*)d_in[13]; const float* bfuse = (const float*)d_in[14];
    float* out = (float*)d_out;

    // workspace layout (floats): qT | k0T | v0T | k1T | v1T | fusedT  (~30.4 MB)
    float* qT     = (float*)d_ws;
    float* k0T    = qT  + (size_t)8192 * 256;
    float* v0T    = k0T + (size_t)2048 * 256;
    float* k1T    = v0T + (size_t)2048 * 256;
    float* v1T    = k1T + (size_t)512 * 256;
    float* fusedT = v1T + (size_t)512 * 256;

    // 1) all projections fused into one dispatch (independent GEMMs overlap)
    proj_k<<<dim3(896), 256, 0, stream>>>(
        query, mem0, mem1,
        Wq, bq, qT, Wk0, bk0, k0T, Wv0, bv0, v0T,
        Wk1, bk1, k1T, Wv1, bv1, v1T);
    // 2) both attention scales -> fusedT [8192][512]
    attn_k<<<dim3(512), 256, 0, stream>>>(qT, k0T, v0T, k1T, v1T, fusedT);
    // 3) out = Wfuse * fused + bfuse  -> d_out [2][256][64][64]
    fuse_k<<<dim3(256, 4), 256, 0, stream>>>(fusedT, Wfuse, bfuse, out);
}

// Round 4
// 113.843 us; speedup vs baseline: 2.3042x; 1.8639x over previous
//
#include <hip/hip_runtime.h>
#include <math.h>

typedef unsigned short u16;
typedef unsigned int u32;
typedef __attribute__((ext_vector_type(8))) short bf16x8;
typedef __attribute__((ext_vector_type(4))) float f32x4;

// ---------------- bf16 helpers (manual RNE; inputs are finite) ----------------
__device__ __forceinline__ u16 f2bf(float x) {
    u32 b = __builtin_bit_cast(u32, x);
    b += 0x7FFFu + ((b >> 16) & 1u);
    return (u16)(b >> 16);
}
__device__ __forceinline__ float bf2f(u16 u) {
    u32 b = ((u32)u) << 16;
    return __builtin_bit_cast(float, b);
}

// Swizzled tiled plane address, in 16-byte units.
// Plane layout: [row/128][c/64] tiles of 1024 units;
// unit-in-tile = (row&127)*8 + (slot ^ (row&7)), slot = (c&63)>>3.
// XOR keeps ds_read_b128 fragment reads bank-conflict-free while the tile is
// copied linearly into LDS (T2 via pre-swizzled global, m173 pattern).
__device__ __forceinline__ size_t sw_unit(int row, int c, int CC) {
    int slot = (c & 63) >> 3;
    return ((size_t)((row >> 7) * CC + (c >> 6)) << 10)
         + (size_t)((row & 127) << 3) + (size_t)(slot ^ (row & 7));
}

// ---------------------------------------------------------------------------
// prep: convert+transpose activations / convert weights into swizzled hi/lo
// bf16 planes.
// ---------------------------------------------------------------------------
__device__ void prep_x(const float* __restrict__ X, int C, int HW, int bl, int PT,
                       u16* __restrict__ dh, u16* __restrict__ dl) {
    __shared__ float Xt[64][65];
    const int t = threadIdx.x;
    const int pt = bl % PT, ct = bl / PT;
    const int p0 = pt * 64, c0 = ct * 64;
    const int b = p0 / HW, hw0 = p0 % HW;
    #pragma unroll
    for (int i = 0; i < 16; i++) {
        int r = (t >> 6) + i * 4;
        Xt[r][t & 63] = X[(size_t)(b * C + c0 + r) * HW + hw0 + (t & 63)];
    }
    __syncthreads();
    const int CC = C >> 6;
    #pragma unroll
    for (int it = 0; it < 2; it++) {
        int id = t + it * 256;
        int px = id >> 3, sl = id & 7;
        bf16x8 hv, lv;
        #pragma unroll
        for (int j = 0; j < 8; j++) {
            float x = Xt[sl * 8 + j][px];
            u16 h = f2bf(x);
            hv[j] = (short)h;
            lv[j] = (short)f2bf(x - bf2f(h));
        }
        size_t unit = sw_unit(p0 + px, c0 + sl * 8, CC);
        *(bf16x8*)(dh + unit * 8) = hv;
        *(bf16x8*)(dl + unit * 8) = lv;
    }
}

__device__ void prep_w(const float* __restrict__ W, int C, int bl,
                       u16* __restrict__ dh, u16* __restrict__ dl) {
    const int t = threadIdx.x;
    const int ot = bl & 3, cc = bl >> 2;
    const int o0 = ot * 64, c0 = cc * 64;
    const int CC = C >> 6;
    #pragma unroll
    for (int it = 0; it < 2; it++) {
        int id = t + it * 256;
        int ol = id >> 3, sl = id & 7;
        int o = o0 + ol, c = c0 + sl * 8;
        const float* wp = W + (size_t)o * C + c;
        float4 a = *(const float4*)wp;
        float4 b2 = *(const float4*)(wp + 4);
        float xs[8] = {a.x, a.y, a.z, a.w, b2.x, b2.y, b2.z, b2.w};
        bf16x8 hv, lv;
        #pragma unroll
        for (int j = 0; j < 8; j++) {
            u16 h = f2bf(xs[j]);
            hv[j] = (short)h;
            lv[j] = (short)f2bf(xs[j] - bf2f(h));
        }
        size_t unit = sw_unit(o, c, CC);
        *(bf16x8*)(dh + unit * 8) = hv;
        *(bf16x8*)(dl + unit * 8) = lv;
    }
}

// W plane offsets in u16 units inside the combined Whi/Wlo buffers
#define OFF_WQ 0
#define OFF_WK0 65536
#define OFF_WV0 163840
#define OFF_WK1 262144
#define OFF_WV1 458752
#define OFF_WFUSE 655360

__global__ __launch_bounds__(256) void prep_k(
    const float* __restrict__ query, const float* __restrict__ mem0, const float* __restrict__ mem1,
    const float* __restrict__ Wq, const float* __restrict__ Wk0, const float* __restrict__ Wv0,
    const float* __restrict__ Wk1, const float* __restrict__ Wv1, const float* __restrict__ Wfuse,
    u16* Xq_hi, u16* Xq_lo, u16* Xm0_hi, u16* Xm0_lo, u16* Xm1_hi, u16* Xm1_lo,
    u16* Whi, u16* Wlo)
{
    const int bx = blockIdx.x;
    if (bx < 512)      prep_x(query, 256, 4096, bx,       128, Xq_hi, Xq_lo);
    else if (bx < 704) prep_x(mem0,  384, 1024, bx - 512,  32, Xm0_hi, Xm0_lo);
    else if (bx < 800) prep_x(mem1,  768,  256, bx - 704,   8, Xm1_hi, Xm1_lo);
    else {
        int r = bx - 800;
        if (r < 16)       prep_w(Wq,    256, r,       Whi + OFF_WQ,    Wlo + OFF_WQ);
        else if (r < 40)  prep_w(Wk0,   384, r - 16,  Whi + OFF_WK0,   Wlo + OFF_WK0);
        else if (r < 64)  prep_w(Wv0,   384, r - 40,  Whi + OFF_WV0,   Wlo + OFF_WV0);
        else if (r < 112) prep_w(Wk1,   768, r - 64,  Whi + OFF_WK1,   Wlo + OFF_WK1);
        else if (r < 160) prep_w(Wv1,   768, r - 112, Whi + OFF_WV1,   Wlo + OFF_WV1);
        else              prep_w(Wfuse, 512, r - 160, Whi + OFF_WFUSE, Wlo + OFF_WFUSE);
    }
}

// ---------------------------------------------------------------------------
// Split-bf16 MFMA GEMM core. D[r][c] = sum_k A[r][k]*B[k][c] (+bias), with
// A,B given as swizzled hi/lo bf16 planes ([row][k] tiles). Block = 128x128,
// 4 waves of 64x64 (4x4 16x16 D-tiles each), KC=64, single-buffered LDS.
// Staging: plain register copy (global bf16x8 load -> LDS store), linear —
// NO global_load_lds builtin (clang-22 segfaulted on it in R2).
// BPL=2: 3-term split (AhiBhi+AloBhi+AhiBlo). BPL=1: B has hi plane only.
// CHMAJ=false: Y[row][256] pixel-major.  CHMAJ=true: Y=out channel-major.
// ---------------------------------------------------------------------------
template<int BPL, bool CHMAJ>
__device__ __forceinline__ void gemm_core(
    const u16* __restrict__ Ahi, const u16* __restrict__ Alo,
    const u16* __restrict__ Bhi, const u16* __restrict__ Blo,
    const float* __restrict__ bias, float* __restrict__ Y,
    int CC, int am, int bn, u16* smem)
{
    constexpr int PL = 2 + BPL;
    const int t = threadIdx.x, lane = t & 63, w = t >> 6;
    const int wr = w >> 1, wc = w & 1;

    f32x4 acc[4][4];
    #pragma unroll
    for (int a = 0; a < 4; a++)
        #pragma unroll
        for (int b = 0; b < 4; b++)
            acc[a][b] = (f32x4){0.f, 0.f, 0.f, 0.f};

    for (int ck = 0; ck < CC; ck++) {
        // ---- stage chunk: linear plane copy, 16B per thread per pass ----
        const size_t aoff = ((size_t)(am * CC + ck)) << 13;  // 8192 u16 per tile
        const size_t boff = ((size_t)(bn * CC + ck)) << 13;
        bf16x8 stg[PL][4];
        #pragma unroll
        for (int it = 0; it < 4; it++) {
            const size_t o = (size_t)(t + it * 256) * 8;
            stg[0][it] = *(const bf16x8*)(Ahi + aoff + o);
            stg[1][it] = *(const bf16x8*)(Alo + aoff + o);
            stg[2][it] = *(const bf16x8*)(Bhi + boff + o);
            if (BPL == 2) stg[3][it] = *(const bf16x8*)(Blo + boff + o);
        }
        __syncthreads();   // previous chunk's compute done before overwrite
        #pragma unroll
        for (int p = 0; p < PL; p++)
            #pragma unroll
            for (int it = 0; it < 4; it++)
                *(bf16x8*)(smem + p * 8192 + (size_t)(t + it * 256) * 8) = stg[p][it];
        __syncthreads();   // chunk landed in LDS

        // ---- compute: 2 k-steps of 32 ----
        #pragma unroll
        for (int kk = 0; kk < 2; kk++) {
            bf16x8 ah[4], al[4], bh[4], bl[4];
            #pragma unroll
            for (int tr = 0; tr < 4; tr++) {
                int row = wr * 64 + tr * 16 + (lane & 15);
                int off = row * 64 + (((kk * 4 + (lane >> 4)) ^ (row & 7)) << 3);
                ah[tr] = *(const bf16x8*)(smem + off);
                al[tr] = *(const bf16x8*)(smem + 8192 + off);
            }
            #pragma unroll
            for (int tc = 0; tc < 4; tc++) {
                int row = wc * 64 + tc * 16 + (lane & 15);
                int off = row * 64 + (((kk * 4 + (lane >> 4)) ^ (row & 7)) << 3);
                bh[tc] = *(const bf16x8*)(smem + 16384 + off);
                if (BPL == 2) bl[tc] = *(const bf16x8*)(smem + 24576 + off);
            }
            #pragma unroll
            for (int tr = 0; tr < 4; tr++)
                #pragma unroll
                for (int tc = 0; tc < 4; tc++) {
                    acc[tr][tc] = __builtin_amdgcn_mfma_f32_16x16x32_bf16(ah[tr], bh[tc], acc[tr][tc], 0, 0, 0);
                    acc[tr][tc] = __builtin_amdgcn_mfma_f32_16x16x32_bf16(al[tr], bh[tc], acc[tr][tc], 0, 0, 0);
                    if (BPL == 2)
                        acc[tr][tc] = __builtin_amdgcn_mfma_f32_16x16x32_bf16(ah[tr], bl[tc], acc[tr][tc], 0, 0, 0);
                }
        }
    }

    // ---- epilogue: D row = (lane>>4)*4+i, col = lane&15 (m89-verified) ----
    if (!CHMAJ) {
        float bv[4];
        #pragma unroll
        for (int tc = 0; tc < 4; tc++)
            bv[tc] = bias[bn * 128 + wc * 64 + tc * 16 + (lane & 15)];
        #pragma unroll
        for (int tr = 0; tr < 4; tr++) {
            #pragma unroll
            for (int i = 0; i < 4; i++) {
                int rp = am * 128 + wr * 64 + tr * 16 + ((lane >> 4) << 2) + i;
                float* yr = Y + (size_t)rp * 256 + bn * 128 + wc * 64 + (lane & 15);
                #pragma unroll
                for (int tc = 0; tc < 4; tc++)
                    yr[tc * 16] = acc[tr][tc][i] + bv[tc];
            }
        }
    } else {
        #pragma unroll
        for (int tr = 0; tr < 4; tr++) {
            #pragma unroll
            for (int i = 0; i < 4; i++) {
                int o = am * 128 + wr * 64 + tr * 16 + ((lane >> 4) << 2) + i;
                float bv = bias[o];
                #pragma unroll
                for (int tc = 0; tc < 4; tc++) {
                    int pcol = bn * 128 + wc * 64 + tc * 16 + (lane & 15);
                    Y[(size_t)((pcol >> 12) * 256 + o) * 4096 + (pcol & 4095)] = acc[tr][tc][i] + bv;
                }
            }
        }
    }
}

// proj: q / k0 / v0 / k1 / v1 in one dispatch (208 blocks)
__global__ __launch_bounds__(256) void projmm_k(
    const u16* __restrict__ Xq_hi, const u16* __restrict__ Xq_lo,
    const u16* __restrict__ Xm0_hi, const u16* __restrict__ Xm0_lo,
    const u16* __restrict__ Xm1_hi, const u16* __restrict__ Xm1_lo,
    const u16* __restrict__ Whi, const u16* __restrict__ Wlo,
    const float* __restrict__ bq, const float* __restrict__ bk0, const float* __restrict__ bv0,
    const float* __restrict__ bk1, const float* __restrict__ bv1,
    float* qT, float* k0T, float* v0T, float* k1T, float* v1T)
{
    __shared__ u16 smem[32768];   // 64 KB
    const int bx = blockIdx.x;
    const u16 *Ah, *Al, *Bh, *Bl; const float* bias; float* Y;
    int CC, am, bn;
    if (bx < 128) {
        am = bx >> 1; bn = bx & 1; CC = 4;
        Ah = Xq_hi; Al = Xq_lo; Bh = Whi + OFF_WQ; Bl = Wlo + OFF_WQ; bias = bq; Y = qT;
    } else if (bx < 192) {
        int r = bx - 128; am = r >> 2; int bnn = r & 3; CC = 6;
        Ah = Xm0_hi; Al = Xm0_lo;
        if (bnn < 2) { Bh = Whi + OFF_WK0; Bl = Wlo + OFF_WK0; bias = bk0; Y = k0T; bn = bnn; }
        else         { Bh = Whi + OFF_WV0; Bl = Wlo + OFF_WV0; bias = bv0; Y = v0T; bn = bnn - 2; }
    } else {
        int r = bx - 192; am = r >> 2; int bnn = r & 3; CC = 12;
        Ah = Xm1_hi; Al = Xm1_lo;
        if (bnn < 2) { Bh = Whi + OFF_WK1; Bl = Wlo + OFF_WK1; bias = bk1; Y = k1T; bn = bnn; }
        else         { Bh = Whi + OFF_WV1; Bl = Wlo + OFF_WV1; bias = bv1; Y = v1T; bn = bnn - 2; }
    }
    gemm_core<2, false>(Ah, Al, Bh, Bl, bias, Y, CC, am, bn, smem);
}

// fuse: out = Wfuse * fused + bfuse (A = Wfuse rows, B = fused pixels), 128 blocks
__global__ __launch_bounds__(256) void fusemm_k(
    const u16* __restrict__ Whi, const u16* __restrict__ Wlo,
    const u16* __restrict__ fhi, const float* __restrict__ bfuse, float* out)
{
    __shared__ u16 smem[24576];   // 48 KB
    const int bx = blockIdx.x;
    gemm_core<1, true>(Whi + OFF_WFUSE, Wlo + OFF_WFUSE, fhi, (const u16*)nullptr,
                       bfuse, out, 8, bx & 1, bx >> 1, smem);
}

// ---------------------------------------------------------------------------
// Attention (unchanged math): thread per (b, head, query-pixel), online softmax
// over WS*WS dilated neighbors. Emits fused directly as swizzled bf16-hi plane.
// ---------------------------------------------------------------------------
template<int WS, int DIL, int SF, int HM, int WM>
__device__ __forceinline__ void attn_one(
    const float* __restrict__ qT, const float* __restrict__ kT,
    const float* __restrict__ vT, u16* __restrict__ fhi,
    int b, int n, int tile, int t, int s_off)
{
    const int qy = (tile >> 2) * 16 + (t >> 4);
    const int qx = (tile & 3) * 16 + (t & 15);
    const int p  = (b * 64 + qy) * 64 + qx;

    float q[32], o[32];
    const float* qp = qT + (size_t)p * 256 + n * 32;
    #pragma unroll
    for (int i = 0; i < 8; i++) {
        float4 v = *(const float4*)(qp + i * 4);
        q[i*4] = v.x; q[i*4+1] = v.y; q[i*4+2] = v.z; q[i*4+3] = v.w;
    }
    #pragma unroll
    for (int d = 0; d < 32; d++) o[d] = 0.f;

    float m = -INFINITY, l = 0.f;
    const int ay = qy / SF, ax = qx / SF;
    const float scale = 0.17677669529663687f;   // 32^-0.5

    for (int jy = 0; jy < WS; jy++) {
        const int ym = ay + (jy - WS / 2) * DIL;
        if (ym < 0 || ym >= HM) continue;
        for (int jx = 0; jx < WS; jx++) {
            const int xm = ax + (jx - WS / 2) * DIL;
            if (xm < 0 || xm >= WM) continue;
            const int base = (((b * HM) + ym) * WM + xm) * 256 + n * 32;
            const float* kp = kT + base;
            float dot = 0.f;
            #pragma unroll
            for (int i = 0; i < 8; i++) {
                float4 kv = *(const float4*)(kp + i * 4);
                dot += q[i*4] * kv.x + q[i*4+1] * kv.y + q[i*4+2] * kv.z + q[i*4+3] * kv.w;
            }
            const float sc = dot * scale;
            if (sc > m) {
                const float corr = __expf(m - sc);
                l *= corr;
                #pragma unroll
                for (int d = 0; d < 32; d++) o[d] *= corr;
                m = sc;
            }
            const float wgt = __expf(sc - m);
            l += wgt;
            const float* vp = vT + base;
            #pragma unroll
            for (int i = 0; i < 8; i++) {
                float4 vv = *(const float4*)(vp + i * 4);
                o[i*4]   += wgt * vv.x; o[i*4+1] += wgt * vv.y;
                o[i*4+2] += wgt * vv.z; o[i*4+3] += wgt * vv.w;
            }
        }
    }

    const float inv = 1.f / l;
    const int k0 = s_off + n * 32;
    #pragma unroll
    for (int mm = 0; mm < 4; mm++) {
        bf16x8 hv;
        #pragma unroll
        for (int j = 0; j < 8; j++) hv[j] = (short)f2bf(o[mm * 8 + j] * inv);
        size_t unit = sw_unit(p, k0 + mm * 8, 8);
        *(bf16x8*)(fhi + unit * 8) = hv;
    }
}

__global__ __launch_bounds__(256) void attn_k(
    const float* __restrict__ qT,
    const float* __restrict__ k0T, const float* __restrict__ v0T,
    const float* __restrict__ k1T, const float* __restrict__ v1T,
    u16* __restrict__ fhi)
{
    const int x = blockIdx.x;
    const int t = threadIdx.x;
    const int s = x >> 8;
    const int r = x & 255;
    const int tile = r & 15;
    const int n = (r >> 4) & 7;
    const int b = r >> 7;
    if (s == 0) attn_one<7, 1, 2, 32, 32>(qT, k0T, v0T, fhi, b, n, tile, t, 0);
    else        attn_one<5, 2, 4, 16, 16>(qT, k1T, v1T, fhi, b, n, tile, t, 256);
}

// ---------------------------------------------------------------------------
extern "C" void kernel_launch(void* const* d_in, const int* in_sizes, int n_in,
                              void* d_out, int out_size, void* d_ws, size_t ws_size,
                              hipStream_t stream)
{
    const float* query = (const float*)d_in[0];
    const float* mem0  = (const float*)d_in[1];
    const float* mem1  = (const float*)d_in[2];
    const float* Wq    = (const float*)d_in[3];  const float* bq    = (const float*)d_in[4];
    const float* Wk0   = (const float*)d_in[5];  const float* bk0   = (const float*)d_in[6];
    const float* Wv0   = (const float*)d_in[7];  const float* bv0   = (const float*)d_in[8];
    const float* Wk1   = (const float*)d_in[9];  const float* bk1   = (const float*)d_in[10];
    const float* Wv1   = (const float*)d_in[11]; const float* bv1   = (const float*)d_in[12];
    const float* Wfuse = (const float*)d_in[13]; const float* bfuse = (const float*)d_in[14];
    float* out = (float*)d_out;

    // workspace layout (bytes, total 29,884,416 = 28.5 MiB)
    char* ws = (char*)d_ws;
    float* qT     = (float*)(ws + 0);          // 8,388,608
    float* k0T    = (float*)(ws + 8388608);    // 2,097,152
    float* v0T    = (float*)(ws + 10485760);   // 2,097,152
    float* k1T    = (float*)(ws + 12582912);   //   524,288
    float* v1T    = (float*)(ws + 13107200);   //   524,288
    u16* Whi      = (u16*)(ws + 13631488);     // 1,572,864
    u16* Wlo      = (u16*)(ws + 15204352);     // 1,572,864
    u16* Xm0_hi   = (u16*)(ws + 16777216);     // 1,572,864
    u16* Xm0_lo   = (u16*)(ws + 18350080);     // 1,572,864
    u16* Xm1_hi   = (u16*)(ws + 19922944);     //   786,432
    u16* Xm1_lo   = (u16*)(ws + 20709376);     //   786,432
    u16* Xq_hi    = (u16*)(ws + 21495808);     // 4,194,304
    u16* Xq_lo    = (u16*)(ws + 25690112);     // 4,194,304
    // fused hi plane (8 MB) aliases Xq_hi+Xq_lo (dead after projmm_k)
    u16* fhi      = Xq_hi;

    prep_k<<<dim3(992), 256, 0, stream>>>(
        query, mem0, mem1, Wq, Wk0, Wv0, Wk1, Wv1, Wfuse,
        Xq_hi, Xq_lo, Xm0_hi, Xm0_lo, Xm1_hi, Xm1_lo, Whi, Wlo);

    projmm_k<<<dim3(208), 256, 0, stream>>>(
        Xq_hi, Xq_lo, Xm0_hi, Xm0_lo, Xm1_hi, Xm1_lo, Whi, Wlo,
        bq, bk0, bv0, bk1, bv1, qT, k0T, v0T, k1T, v1T);

    attn_k<<<dim3(512), 256, 0, stream>>>(qT, k0T, v0T, k1T, v1T, fhi);

    fusemm_k<<<dim3(128), 256, 0, stream>>>(Whi, Wlo, fhi, bfuse, out);
}